// Round 12
// baseline (314.310 us; speedup 1.0000x reference)
//
#include <hip/hip_runtime.h>
#include <stdint.h>

typedef int v4i   __attribute__((ext_vector_type(4)));
typedef int v16i  __attribute__((ext_vector_type(16)));

#define B_    128
#define C_    64
#define H_    56
#define W_    56
#define HW_   3136
#define NELEM (B_*C_*HW_)          // 25,690,112

// workspace layout (bytes)
#define OFF_K0   0                                  // int8 [B][H][W][C] quantized x (NHWC)
#define OFF_K1   ((size_t)NELEM)                    // (unused)
#define OFF_WB   ((size_t)2*NELEM)                  // int8 [2][4][9][64][16] (layer, ci-chunk, tap, co, ci-low)
#define OFF_PAR  (OFF_WB + 2*4*9*64*16)             // float: [0..127] qw, [128..255] qb, [256..383] scale=2^p/7
#define OFF_MAX  (OFF_PAR + 384*4)                  // uint32 absmax bits

// --------------------------- numpy-pairwise-faithful wave reduction (576-elem)
__device__ __forceinline__ float pw_reduce64(float r) {
    r = __fadd_rn(r, __shfl_xor(r, 1, 64));
    r = __fadd_rn(r, __shfl_xor(r, 2, 64));
    r = __fadd_rn(r, __shfl_xor(r, 4, 64));
    r = __fadd_rn(r, __shfl_xor(r, 8, 64));
    r = __fadd_rn(r, __shfl_xor(r, 16, 64));
    r = __fadd_rn(r, __shfl_xor(r, 32, 64));
    return r;
}

// ---------------------------------------------------------------- fused prep
__global__ void k_pre(const float* __restrict__ x, unsigned* __restrict__ maxbits,
                      const float* __restrict__ w1, const float* __restrict__ w2,
                      int8_t* __restrict__ wb, float* __restrict__ par,
                      const float* __restrict__ g1, const float* __restrict__ bb1,
                      const float* __restrict__ mm1, const float* __restrict__ vv1,
                      const float* __restrict__ g2, const float* __restrict__ bb2,
                      const float* __restrict__ mm2, const float* __restrict__ vv2) {
    __shared__ float smax[4];
    const int b = blockIdx.x;
    const int tid = threadIdx.x;
    if (b < 1024) {
        float m = 0.f;
        const int n4 = NELEM / 4;
        for (int i = b * 256 + tid; i < n4; i += 1024 * 256) {
            float4 v = ((const float4*)x)[i];
            m = fmaxf(m, fmaxf(fmaxf(fabsf(v.x), fabsf(v.y)), fmaxf(fabsf(v.z), fabsf(v.w))));
        }
        for (int off = 32; off; off >>= 1) m = fmaxf(m, __shfl_down(m, off, 64));
        if ((tid & 63) == 0) smax[tid >> 6] = m;
        __syncthreads();
        if (tid == 0) {
            float mm = fmaxf(fmaxf(smax[0], smax[1]), fmaxf(smax[2], smax[3]));
            atomicMax(maxbits, __float_as_uint(mm));   // nonneg floats: uint order == float order
        }
    } else if (b < 1056) {
        const int idx = (b - 1024) * 4 + (tid >> 6);
        const int layer = idx >> 6, co = idx & 63;
        const int lane = tid & 63;
        const float* w = (layer ? w2 : w1) + (size_t)co * 576;
        const int base = (lane >> 3) * 72 + (lane & 7);

        float v[9];
#pragma unroll
        for (int i = 0; i < 9; i++) v[i] = w[base + 8 * i];

        float s = v[0];
#pragma unroll
        for (int i = 1; i < 9; i++) s = __fadd_rn(s, v[i]);
        const float mean = __fdiv_rn(pw_reduce64(s), 576.0f);

        float d0 = __fsub_rn(v[0], mean);
        float sq = __fmul_rn(d0, d0);
#pragma unroll
        for (int i = 1; i < 9; i++) {
            float d = __fsub_rn(v[i], mean);
            sq = __fadd_rn(sq, __fmul_rn(d, d));
        }
        const float sig = __fsqrt_rn(__fdiv_rn(pw_reduce64(sq), 575.0f));

        float sa = fabsf(__fdiv_rn(__fsub_rn(v[0], mean), sig));
#pragma unroll
        for (int i = 1; i < 9; i++)
            sa = __fadd_rn(sa, fabsf(__fdiv_rn(__fsub_rn(v[i], mean), sig)));
        const float ma = __fdiv_rn(pw_reduce64(sa), 576.0f);
        const float p  = rintf(log2f(ma));
        if (lane == 0) par[256 + layer * 64 + co] = __fdiv_rn(exp2f(p), 7.0f);

#pragma unroll
        for (int i = 0; i < 9; i++) {
            int ig = base + 8 * i;
            float d = __fsub_rn(v[i], mean);
            int8_t sg = (d > 0.0f) ? (int8_t)1 : ((d < 0.0f) ? (int8_t)-1 : (int8_t)0);
            int ci = ig / 9, tp = ig % 9;
            wb[((((size_t)layer * 4 + (ci >> 4)) * 9 + tp) * 64 + co) * 16 + (ci & 15)] = sg;
        }
    } else {
        if (tid < 128) {
            const int layer = tid >> 6;
            const int c = tid & 63;
            const float* g  = layer ? g2  : g1;
            const float* be = layer ? bb2 : bb1;
            const float* mu = layer ? mm2 : mm1;
            const float* va = layer ? vv2 : vv1;
            const float stdv = __fsqrt_rn(__fadd_rn(va[c], 1e-5f));
            const float w = __fdiv_rn(g[c], stdv);
            const float bb = __fsub_rn(be[c], __fmul_rn(w, mu[c]));
            float aw = fabsf(w), ab = fabsf(bb);
            for (int off = 32; off; off >>= 1) {
                aw = fmaxf(aw, __shfl_xor(aw, off, 64));
                ab = fmaxf(ab, __shfl_xor(ab, off, 64));
            }
            const float Tw = fminf(fmaxf(aw, 1e-10f), 255.0f);
            const float Tb = fminf(fmaxf(ab, 1e-10f), 255.0f);
            {   // quantize(w, 3): n = 7
                float vq = __fdiv_rn(fminf(fmaxf(w, -Tw), Tw), Tw);
                float r  = rintf(__fmul_rn(vq, 7.0f));
                float qf = __fadd_rn(vq, __fsub_rn(__fdiv_rn(r, 7.0f), vq));
                par[layer * 64 + c] = __fmul_rn(qf, Tw);
            }
            {   // quantize(b, 12): n = 4095
                float vq = __fdiv_rn(fminf(fmaxf(bb, -Tb), Tb), Tb);
                float r  = rintf(__fmul_rn(vq, 4095.0f));
                float qf = __fadd_rn(vq, __fsub_rn(__fdiv_rn(r, 4095.0f), vq));
                par[128 + layer * 64 + c] = __fmul_rn(qf, Tb);
            }
        }
    }
}

// ------------------------------------- quantize x -> int8 k0 in NHWC layout
__global__ void k_quant(const float* __restrict__ x, const unsigned* __restrict__ maxbits,
                        int8_t* __restrict__ k8) {
    __shared__ unsigned tile[56 * 17];   // [x][16 ch-dwords + 1 pad]
    const int n = blockIdx.x / H_;
    const int y = blockIdx.x % H_;
    const float T = fminf(fmaxf(__uint_as_float(*maxbits), 1e-10f), 255.0f);
    const double dinv = 1.0 / (double)T;            // correctly-rounded f64 reciprocal
    const int t = threadIdx.x;
    if (t < 224) {
        const int cb = t / 14, xb = t % 14;
        const float* src = x + ((size_t)(n * 64 + 4 * cb)) * HW_ + y * 56 + 4 * xb;
        int kq[4][4];
#pragma unroll
        for (int i = 0; i < 4; i++) {
            float4 v = *(const float4*)(src + (size_t)i * HW_);
            const float e[4] = {v.x, v.y, v.z, v.w};
#pragma unroll
            for (int j = 0; j < 4; j++) {
                const float tc = fminf(fmaxf(e[j], -T), T);
                const float u  = (float)((double)tc * dinv);     // == __fdiv_rn(tc, T)
                kq[i][j] = (int)rintf(__fmul_rn(u, 7.0f));
            }
        }
#pragma unroll
        for (int j = 0; j < 4; j++) {
            const unsigned d = (kq[0][j] & 255) | ((kq[1][j] & 255) << 8) |
                               ((kq[2][j] & 255) << 16) | ((unsigned)(kq[3][j] & 255) << 24);
            tile[(4 * xb + j) * 17 + cb] = d;
        }
    }
    __syncthreads();
    unsigned* dst = (unsigned*)(k8 + ((size_t)(n * 56 + y)) * 56 * 64);
    for (int u = t; u < 896; u += 256)
        dst[u] = tile[(u >> 4) * 17 + (u & 15)];
}

// faithful f32 epilogue chain. qfn shortened via the HW-validated (round-11,
// absmax 0.0) Sterbenz identity y1 == q1: aq = fmul(fdiv_rn(rr,1023), 576),
// computed INLINE (f64 recip-mul) -- no LUT, no LDS traffic, no conflicts.
#define EPI_CHAIN(S_, scf_, xqv_, qwf_, qbf_, OUT_)                         \
    {   const float Sf_ = (float)(S_);                                      \
        const float convf_ = __fmul_rn(Sf_, scf_);                          \
        const float xb_ = (float)((double)convf_ * (1.0 / 576.0));          \
        const float rr_ = rintf(__fmul_rn(xb_, 1023.0f));                   \
        const float q1_ = (float)((double)rr_ * (1.0 / 1023.0));            \
        const float aq_ = __fmul_rn(q1_, 576.0f);                           \
        float vv_ = __fadd_rn(__fadd_rn(__fmul_rn(aq_, qwf_), qbf_), xqv_); \
        OUT_ = fminf(fmaxf(vv_, -1.0f), 1.0f); }

// =================================================== fused conv1+conv2 block
// Round-10 skeleton (90 µs, absmax 0.0) + two zero-LDS-cost instruction cuts:
//  (1) inline Sterbenz qfn (above) -- replaces round-11's conflict-prone LUT
//  (2) conv1 B-fragments in REGISTERS (retry of round-8 WITHOUT the VGPR cap:
//      no min-blocks launch bound -> cap 256; 88+144=~232 regs, no spill;
//      LDS 96.3 KB fits 1 block/CU anyway). Removes 36 of 108 b128 LDS
//      reads per wave-iter-pair (-33% LDS pipe) + their issue slots.
// Keep: lut7, b16 pair-pack, setprio, par hoist, 8-slot rolling buffers.
__global__ __launch_bounds__(448) void k_fused(const int8_t* __restrict__ k0,
                                               const int8_t* __restrict__ wb,
                                               const float* __restrict__ par,
                                               float* __restrict__ fout) {
    __shared__ __align__(16) int8_t wsm[4 * 9 * 64 * 16];       // conv2 weights, 36864 B
    __shared__ __align__(16) int8_t k0b[4 * 8 * 58 * 16];       // 29696 B
    __shared__ __align__(16) int8_t x1b[4 * 8 * 58 * 16];       // 29696 B
    __shared__ float lut7[16];                                  // kc/7, kc in [-7,7]
    const int n = blockIdx.x >> 1;
    const int b = (blockIdx.x & 1) * 28;
    const int tid = threadIdx.x;
    const int wv = tid >> 6, lane = tid & 63;
    const int mbase = wv * 32;
    const int ml = lane & 31;
    const int khalf = lane >> 5;
    const int m = mbase + ml;
    const int ym = m / 56, cm = m % 56;

    // ---- conv1 B-fragments -> registers (compile-time indices throughout)
    v4i bw[9][2][2];    // [tap][kb][t: co=ml / co=32+ml]
#pragma unroll
    for (int s = 0; s < 9; s++)
#pragma unroll
        for (int kb = 0; kb < 2; kb++) {
            const int q = khalf + 2 * kb;
            bw[s][kb][0] = *(const v4i*)(wb + (((q * 9 + s) * 64 + ml) << 4));
            bw[s][kb][1] = *(const v4i*)(wb + (((q * 9 + s) * 64 + 32 + ml) << 4));
        }

    // ---- prologue: conv2 weights -> LDS, k0 rows b-2..b+3, x1b pads, lut7
    const int8_t* wsrc = wb + 36864;     // layer-1 (conv2) block
    for (int u = tid; u < 2304; u += 448)
        *(int4*)(wsm + u * 16) = *(const int4*)(wsrc + u * 16);
    for (int u = tid; u < 1392; u += 448) {
        const int q = u & 3, vv = u >> 2;
        const int rr = vv / 58, xp = vv % 58;
        const int r = b - 2 + rr, xg = xp - 1;
        int4 val = {0, 0, 0, 0};
        if (r >= 0 && r < 56 && xg >= 0 && xg < 56)
            val = *(const int4*)(k0 + (((size_t)(n * 56 + r)) * 56 + xg) * 64 + q * 16);
        *(int4*)(k0b + (((q * 8 + ((r + 2) & 7)) * 58 + xp) << 4)) = val;
    }
    if (tid < 64) {     // x1b pad columns x=0,57 zero (never overwritten after)
        const int q = tid & 3, slot = (tid >> 2) & 7, xs = (tid >> 5) & 1;
        *(int4*)(x1b + (((q * 8 + slot) * 58 + xs * 57) << 4)) = (int4){0, 0, 0, 0};
    }
    if (tid < 15) lut7[tid] = __fdiv_rn((float)(tid - 7), 7.0f);   // == fdiv(kc,7)
    __syncthreads();

    // ---- per-co parameters hoisted out of the iteration loop
    float qwf1[2], qbf1[2], scf1[2], qwf2[2], qbf2[2], scf2[2];
#pragma unroll
    for (int t = 0; t < 2; t++) {
        const int co = ml + t * 32;
        qwf1[t] = par[co];        qbf1[t] = par[128 + co]; scf1[t] = par[256 + co];
        qwf2[t] = par[64 + co];   qbf2[t] = par[192 + co]; scf2[t] = par[320 + co];
    }

    int4 pre[3];
#pragma unroll 1
    for (int i = 0; i < 8; ++i) {
        // -- A: issue next-4-rows k0 global loads early (latency hides under conv1)
        if (i < 7) {
            const int R0 = b + 4 * i + 4;
#pragma unroll
            for (int it = 0; it < 3; ++it) {
                const int u = tid + it * 448;
                int4 val = {0, 0, 0, 0};
                if (u < 928) {
                    const int q = u & 3, vv = u >> 2;
                    const int rr = vv / 58, xp = vv % 58;
                    const int r = R0 + rr, xg = xp - 1;
                    if (r >= 0 && r < 56 && xg >= 0 && xg < 56)
                        val = *(const int4*)(k0 + (((size_t)(n * 56 + r)) * 56 + xg) * 64 + q * 16);
                }
                pre[it] = val;
            }
        }
        // -- B: conv1 chunk i -> x1 rows y1base..y1base+3 (B operands from regs)
        const int y1base = b - 1 + 4 * i;
        {
            v16i acc0, acc1;
#pragma unroll
            for (int z = 0; z < 16; z++) { acc0[z] = 0; acc1[z] = 0; }
            __builtin_amdgcn_s_setprio(1);
#pragma unroll
            for (int s = 0; s < 9; s++) {
                const int ky = s / 3, kx = s % 3;
                const int arow = y1base + ym + ky - 1;          // >= b-2 >= -2
                const int aslot = (arow + 2) & 7;
#pragma unroll
                for (int kb = 0; kb < 2; kb++) {
                    const int q = khalf + 2 * kb;
                    v4i a = *(const v4i*)(k0b + (((q * 8 + aslot) * 58 + cm + kx) << 4));
                    acc0 = __builtin_amdgcn_mfma_i32_32x32x32_i8(a, bw[s][kb][0], acc0, 0, 0, 0);
                    acc1 = __builtin_amdgcn_mfma_i32_32x32x32_i8(a, bw[s][kb][1], acc1, 0, 0, 0);
                }
            }
            __builtin_amdgcn_s_setprio(0);
            // -- C: epilogue1 (T1==1.0 saturation): k2 = rint(out*7) -> x1b
#pragma unroll
            for (int t = 0; t < 2; t++) {
                const int co = ml + t * 32;
                const float qwf = qwf1[t], qbf = qbf1[t], scf = scf1[t];
                const int qc = co >> 4, cl = co & 15;
                const int clw = cl & ~3, cb8 = (cl & 3) * 8;
#pragma unroll
                for (int g = 0; g < 4; g++) {
                    const int mb = mbase + 8 * g + 4 * khalf;   // %4==0, no row straddle
                    const int rl = mb / 56, c0 = mb % 56;
                    const int y1g = y1base + rl;
                    const bool vrow = (y1g >= 0) && (y1g <= 55);   // else zero value
                    const bool wen  = (y1g <= b + 28);             // beyond strip: skip
                    const int ksl = (y1g + 2) & 7;
                    const int xsl = (y1g + 1) & 7;
                    const int resb = (qc * 8 + ksl) * 58 + c0 + 1;
                    const int outb = (qc * 8 + xsl) * 58 + c0 + 1;
#pragma unroll
                    for (int i4 = 0; i4 < 4; i4++) {
                        const int S = t ? acc1[4 * g + i4] : acc0[4 * g + i4];  // |S|<=4032 exact
                        const unsigned wd = *(const unsigned*)(k0b + ((resb + i4) << 4) + clw);
                        const int kc = (int)(int8_t)(wd >> cb8);
                        const float xqv = lut7[kc + 7];            // == __fdiv_rn(kc,7)
                        float val; EPI_CHAIN(S, scf, xqv, qwf, qbf, val);
                        int k2 = (int)rintf(__fmul_rn(val, 7.0f));
                        if (!vrow) k2 = 0;
                        // b16 pair-pack: lane pair (l, l^1) -> one u16 store by even lane
                        const unsigned lowb = (unsigned)(k2 & 255);
                        const unsigned hib  = (unsigned)__shfl_xor((int)(lowb << 8), 1, 64);
                        if (wen && (ml & 1) == 0)
                            *(uint16_t*)(x1b + ((outb + i4) << 4) + (cl & ~1)) =
                                (uint16_t)(lowb | hib);
                    }
                }
            }
        }
        __syncthreads();   // conv1 k0b reads + x1b writes fenced

        // -- E: publish prefetched k0 rows (slots freed by conv1 chunk i)
        if (i < 7) {
            const int R0 = b + 4 * i + 4;
#pragma unroll
            for (int it = 0; it < 3; ++it) {
                const int u = tid + it * 448;
                if (u < 928) {
                    const int q = u & 3, vv = u >> 2;
                    const int rr = vv / 58, xp = vv % 58;
                    const int r = R0 + rr;
                    *(int4*)(k0b + (((q * 8 + ((r + 2) & 7)) * 58 + xp) << 4)) = pre[it];
                }
            }
        }
        // -- F: conv2 chunk i-1 -> out rows y2base..y2base+3 (always in-image)
        if (i >= 1) {
            const int y2base = b + 4 * (i - 1);
            v16i acc0, acc1;
#pragma unroll
            for (int z = 0; z < 16; z++) { acc0[z] = 0; acc1[z] = 0; }
            __builtin_amdgcn_s_setprio(1);
#pragma unroll
            for (int s = 0; s < 9; s++) {
                const int ky = s / 3, kx = s % 3;
                const int arow = y2base + ym + ky - 1;          // >= b-1 >= -1
                const int aslot = (arow + 1) & 7;
#pragma unroll
                for (int kb = 0; kb < 2; kb++) {
                    const int q = khalf + 2 * kb;
                    v4i a  = *(const v4i*)(x1b + (((q * 8 + aslot) * 58 + cm + kx) << 4));
                    v4i b0 = *(const v4i*)(wsm + (((q * 9 + s) * 64 + ml) << 4));
                    v4i b1 = *(const v4i*)(wsm + (((q * 9 + s) * 64 + 32 + ml) << 4));
                    acc0 = __builtin_amdgcn_mfma_i32_32x32x32_i8(a, b0, acc0, 0, 0, 0);
                    acc1 = __builtin_amdgcn_mfma_i32_32x32x32_i8(a, b1, acc1, 0, 0, 0);
                }
            }
            __builtin_amdgcn_s_setprio(0);
#pragma unroll
            for (int t = 0; t < 2; t++) {
                const int co = ml + t * 32;
                const float qwf = qwf2[t], qbf = qbf2[t], scf = scf2[t];
                const int qc = co >> 4, cl = co & 15;
                const int clw = cl & ~3, cb8 = (cl & 3) * 8;
#pragma unroll
                for (int g = 0; g < 4; g++) {
                    const int mb = mbase + 8 * g + 4 * khalf;
                    const int rl = mb / 56, c0 = mb % 56;
                    const int y2g = y2base + rl;
                    const int xsl = (y2g + 1) & 7;
                    const int resb = (qc * 8 + xsl) * 58 + c0 + 1;
                    float vals[4];
#pragma unroll
                    for (int i4 = 0; i4 < 4; i4++) {
                        const int S = t ? acc1[4 * g + i4] : acc0[4 * g + i4];
                        const unsigned wd = *(const unsigned*)(x1b + ((resb + i4) << 4) + clw);
                        const int kc = (int)(int8_t)(wd >> cb8);
                        const float xqv = lut7[kc + 7];            // == __fdiv_rn(kc,7)
                        EPI_CHAIN(S, scf, xqv, qwf, qbf, vals[i4]);
                    }
                    float4 o = make_float4(vals[0], vals[1], vals[2], vals[3]);
                    *(float4*)(fout + ((size_t)(n * 64 + co)) * HW_ + y2g * 56 + c0) = o;
                }
            }
        }
        if (i < 7) __syncthreads();   // x1b/k0b writes fenced from next iter's readers
    }
}

// ----------------------------------------------------------------- launcher
extern "C" void kernel_launch(void* const* d_in, const int* in_sizes, int n_in,
                              void* d_out, int out_size, void* d_ws, size_t ws_size,
                              hipStream_t stream) {
    const float* x  = (const float*)d_in[0];
    const float* w1 = (const float*)d_in[1];
    const float* w2 = (const float*)d_in[2];
    const float* g1 = (const float*)d_in[3];
    const float* b1 = (const float*)d_in[4];
    const float* m1 = (const float*)d_in[5];
    const float* v1 = (const float*)d_in[6];
    const float* g2 = (const float*)d_in[7];
    const float* b2 = (const float*)d_in[8];
    const float* m2 = (const float*)d_in[9];
    const float* v2 = (const float*)d_in[10];

    char* ws = (char*)d_ws;
    int8_t*  k0  = (int8_t*)(ws + OFF_K0);
    int8_t*  wbp = (int8_t*)(ws + OFF_WB);
    float*   par = (float*)(ws + OFF_PAR);
    unsigned* mx = (unsigned*)(ws + OFF_MAX);

    hipMemsetAsync(mx, 0, 4, stream);
    k_pre<<<1057, 256, 0, stream>>>(x, mx, w1, w2, wbp, par,
                                    g1, b1, m1, v1, g2, b2, m2, v2);
    k_quant<<<B_ * H_, 256, 0, stream>>>(x, mx, k0);
    k_fused<<<B_ * 2, 448, 0, stream>>>(k0, wbp, par, (float*)d_out);
}

// Round 13
// 306.362 us; speedup vs baseline: 1.0259x; 1.0259x over previous
//
#include <hip/hip_runtime.h>
#include <stdint.h>

typedef int v4i   __attribute__((ext_vector_type(4)));
typedef int v16i  __attribute__((ext_vector_type(16)));

#define B_    128
#define C_    64
#define H_    56
#define W_    56
#define HW_   3136
#define NELEM (B_*C_*HW_)          // 25,690,112

// workspace layout (bytes)
#define OFF_K0   0                                  // int8 [B][H][W][C] quantized x (NHWC)
#define OFF_K1   ((size_t)NELEM)                    // (unused)
#define OFF_WB   ((size_t)2*NELEM)                  // int8 [2][4][9][64][16] (layer, ci-chunk, tap, co, ci-low)
#define OFF_PAR  (OFF_WB + 2*4*9*64*16)             // float: [0..127] qw, [128..255] qb, [256..383] scale=2^p/7
#define OFF_MAX  (OFF_PAR + 384*4)                  // uint32 absmax bits

// --------------------------- numpy-pairwise-faithful wave reduction (576-elem)
__device__ __forceinline__ float pw_reduce64(float r) {
    r = __fadd_rn(r, __shfl_xor(r, 1, 64));
    r = __fadd_rn(r, __shfl_xor(r, 2, 64));
    r = __fadd_rn(r, __shfl_xor(r, 4, 64));
    r = __fadd_rn(r, __shfl_xor(r, 8, 64));
    r = __fadd_rn(r, __shfl_xor(r, 16, 64));
    r = __fadd_rn(r, __shfl_xor(r, 32, 64));
    return r;
}

// ---------------------------------------------------------------- fused prep
__global__ void k_pre(const float* __restrict__ x, unsigned* __restrict__ maxbits,
                      const float* __restrict__ w1, const float* __restrict__ w2,
                      int8_t* __restrict__ wb, float* __restrict__ par,
                      const float* __restrict__ g1, const float* __restrict__ bb1,
                      const float* __restrict__ mm1, const float* __restrict__ vv1,
                      const float* __restrict__ g2, const float* __restrict__ bb2,
                      const float* __restrict__ mm2, const float* __restrict__ vv2) {
    __shared__ float smax[4];
    const int b = blockIdx.x;
    const int tid = threadIdx.x;
    if (b < 1024) {
        float m = 0.f;
        const int n4 = NELEM / 4;
        for (int i = b * 256 + tid; i < n4; i += 1024 * 256) {
            float4 v = ((const float4*)x)[i];
            m = fmaxf(m, fmaxf(fmaxf(fabsf(v.x), fabsf(v.y)), fmaxf(fabsf(v.z), fabsf(v.w))));
        }
        for (int off = 32; off; off >>= 1) m = fmaxf(m, __shfl_down(m, off, 64));
        if ((tid & 63) == 0) smax[tid >> 6] = m;
        __syncthreads();
        if (tid == 0) {
            float mm = fmaxf(fmaxf(smax[0], smax[1]), fmaxf(smax[2], smax[3]));
            atomicMax(maxbits, __float_as_uint(mm));   // nonneg floats: uint order == float order
        }
    } else if (b < 1056) {
        const int idx = (b - 1024) * 4 + (tid >> 6);
        const int layer = idx >> 6, co = idx & 63;
        const int lane = tid & 63;
        const float* w = (layer ? w2 : w1) + (size_t)co * 576;
        const int base = (lane >> 3) * 72 + (lane & 7);

        float v[9];
#pragma unroll
        for (int i = 0; i < 9; i++) v[i] = w[base + 8 * i];

        float s = v[0];
#pragma unroll
        for (int i = 1; i < 9; i++) s = __fadd_rn(s, v[i]);
        const float mean = __fdiv_rn(pw_reduce64(s), 576.0f);

        float d0 = __fsub_rn(v[0], mean);
        float sq = __fmul_rn(d0, d0);
#pragma unroll
        for (int i = 1; i < 9; i++) {
            float d = __fsub_rn(v[i], mean);
            sq = __fadd_rn(sq, __fmul_rn(d, d));
        }
        const float sig = __fsqrt_rn(__fdiv_rn(pw_reduce64(sq), 575.0f));

        float sa = fabsf(__fdiv_rn(__fsub_rn(v[0], mean), sig));
#pragma unroll
        for (int i = 1; i < 9; i++)
            sa = __fadd_rn(sa, fabsf(__fdiv_rn(__fsub_rn(v[i], mean), sig)));
        const float ma = __fdiv_rn(pw_reduce64(sa), 576.0f);
        const float p  = rintf(log2f(ma));
        if (lane == 0) par[256 + layer * 64 + co] = __fdiv_rn(exp2f(p), 7.0f);

#pragma unroll
        for (int i = 0; i < 9; i++) {
            int ig = base + 8 * i;
            float d = __fsub_rn(v[i], mean);
            int8_t sg = (d > 0.0f) ? (int8_t)1 : ((d < 0.0f) ? (int8_t)-1 : (int8_t)0);
            int ci = ig / 9, tp = ig % 9;
            wb[((((size_t)layer * 4 + (ci >> 4)) * 9 + tp) * 64 + co) * 16 + (ci & 15)] = sg;
        }
    } else {
        if (tid < 128) {
            const int layer = tid >> 6;
            const int c = tid & 63;
            const float* g  = layer ? g2  : g1;
            const float* be = layer ? bb2 : bb1;
            const float* mu = layer ? mm2 : mm1;
            const float* va = layer ? vv2 : vv1;
            const float stdv = __fsqrt_rn(__fadd_rn(va[c], 1e-5f));
            const float w = __fdiv_rn(g[c], stdv);
            const float bb = __fsub_rn(be[c], __fmul_rn(w, mu[c]));
            float aw = fabsf(w), ab = fabsf(bb);
            for (int off = 32; off; off >>= 1) {
                aw = fmaxf(aw, __shfl_xor(aw, off, 64));
                ab = fmaxf(ab, __shfl_xor(ab, off, 64));
            }
            const float Tw = fminf(fmaxf(aw, 1e-10f), 255.0f);
            const float Tb = fminf(fmaxf(ab, 1e-10f), 255.0f);
            {   // quantize(w, 3): n = 7
                float vq = __fdiv_rn(fminf(fmaxf(w, -Tw), Tw), Tw);
                float r  = rintf(__fmul_rn(vq, 7.0f));
                float qf = __fadd_rn(vq, __fsub_rn(__fdiv_rn(r, 7.0f), vq));
                par[layer * 64 + c] = __fmul_rn(qf, Tw);
            }
            {   // quantize(b, 12): n = 4095
                float vq = __fdiv_rn(fminf(fmaxf(bb, -Tb), Tb), Tb);
                float r  = rintf(__fmul_rn(vq, 4095.0f));
                float qf = __fadd_rn(vq, __fsub_rn(__fdiv_rn(r, 4095.0f), vq));
                par[128 + layer * 64 + c] = __fmul_rn(qf, Tb);
            }
        }
    }
}

// ------------------------------------- quantize x -> int8 k0 in NHWC layout
__global__ void k_quant(const float* __restrict__ x, const unsigned* __restrict__ maxbits,
                        int8_t* __restrict__ k8) {
    __shared__ unsigned tile[56 * 17];   // [x][16 ch-dwords + 1 pad]
    const int n = blockIdx.x / H_;
    const int y = blockIdx.x % H_;
    const float T = fminf(fmaxf(__uint_as_float(*maxbits), 1e-10f), 255.0f);
    const double dinv = 1.0 / (double)T;            // correctly-rounded f64 reciprocal
    const int t = threadIdx.x;
    if (t < 224) {
        const int cb = t / 14, xb = t % 14;
        const float* src = x + ((size_t)(n * 64 + 4 * cb)) * HW_ + y * 56 + 4 * xb;
        int kq[4][4];
#pragma unroll
        for (int i = 0; i < 4; i++) {
            float4 v = *(const float4*)(src + (size_t)i * HW_);
            const float e[4] = {v.x, v.y, v.z, v.w};
#pragma unroll
            for (int j = 0; j < 4; j++) {
                const float tc = fminf(fmaxf(e[j], -T), T);
                const float u  = (float)((double)tc * dinv);     // == __fdiv_rn(tc, T)
                kq[i][j] = (int)rintf(__fmul_rn(u, 7.0f));
            }
        }
#pragma unroll
        for (int j = 0; j < 4; j++) {
            const unsigned d = (kq[0][j] & 255) | ((kq[1][j] & 255) << 8) |
                               ((kq[2][j] & 255) << 16) | ((unsigned)(kq[3][j] & 255) << 24);
            tile[(4 * xb + j) * 17 + cb] = d;
        }
    }
    __syncthreads();
    unsigned* dst = (unsigned*)(k8 + ((size_t)(n * 56 + y)) * 56 * 64);
    for (int u = t; u < 896; u += 256)
        dst[u] = tile[(u >> 4) * 17 + (u & 15)];
}

// faithful f32 epilogue chain. qfn shortened via the HW-validated (rounds
// 11/12, absmax 0.0) Sterbenz identity y1 == q1: aq = fmul(fdiv_rn(rr,1023),
// 576), computed INLINE (f64 recip-mul) -- no LUT, no LDS traffic.
#define EPI_CHAIN(S_, scf_, xqv_, qwf_, qbf_, OUT_)                         \
    {   const float Sf_ = (float)(S_);                                      \
        const float convf_ = __fmul_rn(Sf_, scf_);                          \
        const float xb_ = (float)((double)convf_ * (1.0 / 576.0));          \
        const float rr_ = rintf(__fmul_rn(xb_, 1023.0f));                   \
        const float q1_ = (float)((double)rr_ * (1.0 / 1023.0));            \
        const float aq_ = __fmul_rn(q1_, 576.0f);                           \
        float vv_ = __fadd_rn(__fadd_rn(__fmul_rn(aq_, qwf_), qbf_), xqv_); \
        OUT_ = fminf(fmaxf(vv_, -1.0f), 1.0f); }

// =================================================== fused conv1+conv2 block
// EXACT round-10 structure (90 µs, absmax 0.0: LDS-resident weights BOTH
// layers, 448 thr, 8-slot rolling buffers, b16 pair-pack, lut7, setprio,
// par hoist, __launch_bounds__(448,2) -> VGPR 88, no spill) with the one
// proven upgrade: the inline-Sterbenz EPI chain (saves fadd+fsub/output,
// zero LDS cost -- unlike r11's LUT [+conflicts] and r12's reg-B [spill]).
__global__ __launch_bounds__(448, 2) void k_fused(const int8_t* __restrict__ k0,
                                                  const int8_t* __restrict__ wb,
                                                  const float* __restrict__ par,
                                                  float* __restrict__ fout) {
    __shared__ __align__(16) int8_t wsm[2 * 4 * 9 * 64 * 16];   // both layers, 73728 B
    __shared__ __align__(16) int8_t k0b[4 * 8 * 58 * 16];       // 29696 B
    __shared__ __align__(16) int8_t x1b[4 * 8 * 58 * 16];       // 29696 B
    __shared__ float lut7[16];                                  // kc/7, kc in [-7,7]
    const int n = blockIdx.x >> 1;
    const int b = (blockIdx.x & 1) * 28;
    const int tid = threadIdx.x;
    const int wv = tid >> 6, lane = tid & 63;
    const int mbase = wv * 32;
    const int ml = lane & 31;
    const int khalf = lane >> 5;
    const int m = mbase + ml;
    const int ym = m / 56, cm = m % 56;

    // ---- prologue: weights (both layers), k0 rows b-2..b+3, x1b pads, lut7
    for (int u = tid; u < 4608; u += 448)
        *(int4*)(wsm + u * 16) = *(const int4*)(wb + (size_t)u * 16);
    for (int u = tid; u < 1392; u += 448) {
        const int q = u & 3, vv = u >> 2;
        const int rr = vv / 58, xp = vv % 58;
        const int r = b - 2 + rr, xg = xp - 1;
        int4 val = {0, 0, 0, 0};
        if (r >= 0 && r < 56 && xg >= 0 && xg < 56)
            val = *(const int4*)(k0 + (((size_t)(n * 56 + r)) * 56 + xg) * 64 + q * 16);
        *(int4*)(k0b + (((q * 8 + ((r + 2) & 7)) * 58 + xp) << 4)) = val;
    }
    if (tid < 64) {     // x1b pad columns x=0,57 zero (never overwritten after)
        const int q = tid & 3, slot = (tid >> 2) & 7, xs = (tid >> 5) & 1;
        *(int4*)(x1b + (((q * 8 + slot) * 58 + xs * 57) << 4)) = (int4){0, 0, 0, 0};
    }
    if (tid < 15) lut7[tid] = __fdiv_rn((float)(tid - 7), 7.0f);   // == fdiv(kc,7)
    __syncthreads();

    // ---- per-co parameters hoisted out of the iteration loop
    float qwf1[2], qbf1[2], scf1[2], qwf2[2], qbf2[2], scf2[2];
#pragma unroll
    for (int t = 0; t < 2; t++) {
        const int co = ml + t * 32;
        qwf1[t] = par[co];        qbf1[t] = par[128 + co]; scf1[t] = par[256 + co];
        qwf2[t] = par[64 + co];   qbf2[t] = par[192 + co]; scf2[t] = par[320 + co];
    }

    int4 pre[3];
#pragma unroll 1
    for (int i = 0; i < 8; ++i) {
        // -- A: issue next-4-rows k0 global loads early (latency hides under conv1)
        if (i < 7) {
            const int R0 = b + 4 * i + 4;
#pragma unroll
            for (int it = 0; it < 3; ++it) {
                const int u = tid + it * 448;
                int4 val = {0, 0, 0, 0};
                if (u < 928) {
                    const int q = u & 3, vv = u >> 2;
                    const int rr = vv / 58, xp = vv % 58;
                    const int r = R0 + rr, xg = xp - 1;
                    if (r >= 0 && r < 56 && xg >= 0 && xg < 56)
                        val = *(const int4*)(k0 + (((size_t)(n * 56 + r)) * 56 + xg) * 64 + q * 16);
                }
                pre[it] = val;
            }
        }
        // -- B: conv1 chunk i -> x1 rows y1base..y1base+3
        const int y1base = b - 1 + 4 * i;
        {
            v16i acc0, acc1;
#pragma unroll
            for (int z = 0; z < 16; z++) { acc0[z] = 0; acc1[z] = 0; }
            __builtin_amdgcn_s_setprio(1);
#pragma unroll
            for (int s = 0; s < 9; s++) {
                const int ky = s / 3, kx = s % 3;
                const int arow = y1base + ym + ky - 1;          // >= b-2 >= -2
                const int aslot = (arow + 2) & 7;
#pragma unroll
                for (int kb = 0; kb < 2; kb++) {
                    const int q = khalf + 2 * kb;
                    v4i a  = *(const v4i*)(k0b + (((q * 8 + aslot) * 58 + cm + kx) << 4));
                    v4i b0 = *(const v4i*)(wsm + (((q * 9 + s) * 64 + ml) << 4));
                    v4i b1 = *(const v4i*)(wsm + (((q * 9 + s) * 64 + 32 + ml) << 4));
                    acc0 = __builtin_amdgcn_mfma_i32_32x32x32_i8(a, b0, acc0, 0, 0, 0);
                    acc1 = __builtin_amdgcn_mfma_i32_32x32x32_i8(a, b1, acc1, 0, 0, 0);
                }
            }
            __builtin_amdgcn_s_setprio(0);
            // -- C: epilogue1 (T1==1.0 saturation): k2 = rint(out*7) -> x1b
#pragma unroll
            for (int t = 0; t < 2; t++) {
                const int co = ml + t * 32;
                const float qwf = qwf1[t], qbf = qbf1[t], scf = scf1[t];
                const int qc = co >> 4, cl = co & 15;
                const int clw = cl & ~3, cb8 = (cl & 3) * 8;
#pragma unroll
                for (int g = 0; g < 4; g++) {
                    const int mb = mbase + 8 * g + 4 * khalf;   // %4==0, no row straddle
                    const int rl = mb / 56, c0 = mb % 56;
                    const int y1g = y1base + rl;
                    const bool vrow = (y1g >= 0) && (y1g <= 55);   // else zero value
                    const bool wen  = (y1g <= b + 28);             // beyond strip: skip
                    const int ksl = (y1g + 2) & 7;
                    const int xsl = (y1g + 1) & 7;
                    const int resb = (qc * 8 + ksl) * 58 + c0 + 1;
                    const int outb = (qc * 8 + xsl) * 58 + c0 + 1;
#pragma unroll
                    for (int i4 = 0; i4 < 4; i4++) {
                        const int S = t ? acc1[4 * g + i4] : acc0[4 * g + i4];  // |S|<=4032 exact
                        const unsigned wd = *(const unsigned*)(k0b + ((resb + i4) << 4) + clw);
                        const int kc = (int)(int8_t)(wd >> cb8);
                        const float xqv = lut7[kc + 7];            // == __fdiv_rn(kc,7)
                        float val; EPI_CHAIN(S, scf, xqv, qwf, qbf, val);
                        int k2 = (int)rintf(__fmul_rn(val, 7.0f));
                        if (!vrow) k2 = 0;
                        // b16 pair-pack: lane pair (l, l^1) -> one u16 store by even lane
                        const unsigned lowb = (unsigned)(k2 & 255);
                        const unsigned hib  = (unsigned)__shfl_xor((int)(lowb << 8), 1, 64);
                        if (wen && (ml & 1) == 0)
                            *(uint16_t*)(x1b + ((outb + i4) << 4) + (cl & ~1)) =
                                (uint16_t)(lowb | hib);
                    }
                }
            }
        }
        __syncthreads();   // conv1 k0b reads + x1b writes fenced

        // -- E: publish prefetched k0 rows (slots freed by conv1 chunk i)
        if (i < 7) {
            const int R0 = b + 4 * i + 4;
#pragma unroll
            for (int it = 0; it < 3; ++it) {
                const int u = tid + it * 448;
                if (u < 928) {
                    const int q = u & 3, vv = u >> 2;
                    const int rr = vv / 58, xp = vv % 58;
                    const int r = R0 + rr;
                    *(int4*)(k0b + (((q * 8 + ((r + 2) & 7)) * 58 + xp) << 4)) = pre[it];
                }
            }
        }
        // -- F: conv2 chunk i-1 -> out rows y2base..y2base+3 (always in-image)
        if (i >= 1) {
            const int y2base = b + 4 * (i - 1);
            v16i acc0, acc1;
#pragma unroll
            for (int z = 0; z < 16; z++) { acc0[z] = 0; acc1[z] = 0; }
            __builtin_amdgcn_s_setprio(1);
#pragma unroll
            for (int s = 0; s < 9; s++) {
                const int ky = s / 3, kx = s % 3;
                const int arow = y2base + ym + ky - 1;          // >= b-1 >= -1
                const int aslot = (arow + 1) & 7;
#pragma unroll
                for (int kb = 0; kb < 2; kb++) {
                    const int q = khalf + 2 * kb;
                    v4i a  = *(const v4i*)(x1b + (((q * 8 + aslot) * 58 + cm + kx) << 4));
                    v4i b0 = *(const v4i*)(wsm + 36864 + (((q * 9 + s) * 64 + ml) << 4));
                    v4i b1 = *(const v4i*)(wsm + 36864 + (((q * 9 + s) * 64 + 32 + ml) << 4));
                    acc0 = __builtin_amdgcn_mfma_i32_32x32x32_i8(a, b0, acc0, 0, 0, 0);
                    acc1 = __builtin_amdgcn_mfma_i32_32x32x32_i8(a, b1, acc1, 0, 0, 0);
                }
            }
            __builtin_amdgcn_s_setprio(0);
#pragma unroll
            for (int t = 0; t < 2; t++) {
                const int co = ml + t * 32;
                const float qwf = qwf2[t], qbf = qbf2[t], scf = scf2[t];
                const int qc = co >> 4, cl = co & 15;
                const int clw = cl & ~3, cb8 = (cl & 3) * 8;
#pragma unroll
                for (int g = 0; g < 4; g++) {
                    const int mb = mbase + 8 * g + 4 * khalf;
                    const int rl = mb / 56, c0 = mb % 56;
                    const int y2g = y2base + rl;
                    const int xsl = (y2g + 1) & 7;
                    const int resb = (qc * 8 + xsl) * 58 + c0 + 1;
                    float vals[4];
#pragma unroll
                    for (int i4 = 0; i4 < 4; i4++) {
                        const int S = t ? acc1[4 * g + i4] : acc0[4 * g + i4];
                        const unsigned wd = *(const unsigned*)(x1b + ((resb + i4) << 4) + clw);
                        const int kc = (int)(int8_t)(wd >> cb8);
                        const float xqv = lut7[kc + 7];            // == __fdiv_rn(kc,7)
                        EPI_CHAIN(S, scf, xqv, qwf, qbf, vals[i4]);
                    }
                    float4 o = make_float4(vals[0], vals[1], vals[2], vals[3]);
                    *(float4*)(fout + ((size_t)(n * 64 + co)) * HW_ + y2g * 56 + c0) = o;
                }
            }
        }
        if (i < 7) __syncthreads();   // x1b/k0b writes fenced from next iter's readers
    }
}

// ----------------------------------------------------------------- launcher
extern "C" void kernel_launch(void* const* d_in, const int* in_sizes, int n_in,
                              void* d_out, int out_size, void* d_ws, size_t ws_size,
                              hipStream_t stream) {
    const float* x  = (const float*)d_in[0];
    const float* w1 = (const float*)d_in[1];
    const float* w2 = (const float*)d_in[2];
    const float* g1 = (const float*)d_in[3];
    const float* b1 = (const float*)d_in[4];
    const float* m1 = (const float*)d_in[5];
    const float* v1 = (const float*)d_in[6];
    const float* g2 = (const float*)d_in[7];
    const float* b2 = (const float*)d_in[8];
    const float* m2 = (const float*)d_in[9];
    const float* v2 = (const float*)d_in[10];

    char* ws = (char*)d_ws;
    int8_t*  k0  = (int8_t*)(ws + OFF_K0);
    int8_t*  wbp = (int8_t*)(ws + OFF_WB);
    float*   par = (float*)(ws + OFF_PAR);
    unsigned* mx = (unsigned*)(ws + OFF_MAX);

    hipMemsetAsync(mx, 0, 4, stream);
    k_pre<<<1057, 256, 0, stream>>>(x, mx, w1, w2, wbp, par,
                                    g1, b1, m1, v1, g2, b2, m2, v2);
    k_quant<<<B_ * H_, 256, 0, stream>>>(x, mx, k0);
    k_fused<<<B_ * 2, 448, 0, stream>>>(k0, wbp, par, (float*)d_out);
}

// Round 14
// 286.629 us; speedup vs baseline: 1.0966x; 1.0688x over previous
//
#include <hip/hip_runtime.h>
#include <stdint.h>

typedef int v4i   __attribute__((ext_vector_type(4)));
typedef int v16i  __attribute__((ext_vector_type(16)));

#define B_    128
#define C_    64
#define H_    56
#define W_    56
#define HW_   3136
#define NELEM (B_*C_*HW_)          // 25,690,112

// workspace layout (bytes) -- k0/k1 regions now unused (quant fused into k_fused)
#define OFF_WB   ((size_t)2*NELEM)                  // int8 [2][4][9][64][16] (layer, ci-chunk, tap, co, ci-low)
#define OFF_PAR  (OFF_WB + 2*4*9*64*16)             // float: [0..127] qw, [128..255] qb, [256..383] scale=2^p/7
#define OFF_MAX  (OFF_PAR + 384*4)                  // uint32 absmax bits

// --------------------------- numpy-pairwise-faithful wave reduction (576-elem)
__device__ __forceinline__ float pw_reduce64(float r) {
    r = __fadd_rn(r, __shfl_xor(r, 1, 64));
    r = __fadd_rn(r, __shfl_xor(r, 2, 64));
    r = __fadd_rn(r, __shfl_xor(r, 4, 64));
    r = __fadd_rn(r, __shfl_xor(r, 8, 64));
    r = __fadd_rn(r, __shfl_xor(r, 16, 64));
    r = __fadd_rn(r, __shfl_xor(r, 32, 64));
    return r;
}

// ---------------------------------------------------------------- fused prep
__global__ void k_pre(const float* __restrict__ x, unsigned* __restrict__ maxbits,
                      const float* __restrict__ w1, const float* __restrict__ w2,
                      int8_t* __restrict__ wb, float* __restrict__ par,
                      const float* __restrict__ g1, const float* __restrict__ bb1,
                      const float* __restrict__ mm1, const float* __restrict__ vv1,
                      const float* __restrict__ g2, const float* __restrict__ bb2,
                      const float* __restrict__ mm2, const float* __restrict__ vv2) {
    __shared__ float smax[4];
    const int b = blockIdx.x;
    const int tid = threadIdx.x;
    if (b < 1024) {
        float m = 0.f;
        const int n4 = NELEM / 4;
        for (int i = b * 256 + tid; i < n4; i += 1024 * 256) {
            float4 v = ((const float4*)x)[i];
            m = fmaxf(m, fmaxf(fmaxf(fabsf(v.x), fabsf(v.y)), fmaxf(fabsf(v.z), fabsf(v.w))));
        }
        for (int off = 32; off; off >>= 1) m = fmaxf(m, __shfl_down(m, off, 64));
        if ((tid & 63) == 0) smax[tid >> 6] = m;
        __syncthreads();
        if (tid == 0) {
            float mm = fmaxf(fmaxf(smax[0], smax[1]), fmaxf(smax[2], smax[3]));
            atomicMax(maxbits, __float_as_uint(mm));   // nonneg floats: uint order == float order
        }
    } else if (b < 1056) {
        const int idx = (b - 1024) * 4 + (tid >> 6);
        const int layer = idx >> 6, co = idx & 63;
        const int lane = tid & 63;
        const float* w = (layer ? w2 : w1) + (size_t)co * 576;
        const int base = (lane >> 3) * 72 + (lane & 7);

        float v[9];
#pragma unroll
        for (int i = 0; i < 9; i++) v[i] = w[base + 8 * i];

        float s = v[0];
#pragma unroll
        for (int i = 1; i < 9; i++) s = __fadd_rn(s, v[i]);
        const float mean = __fdiv_rn(pw_reduce64(s), 576.0f);

        float d0 = __fsub_rn(v[0], mean);
        float sq = __fmul_rn(d0, d0);
#pragma unroll
        for (int i = 1; i < 9; i++) {
            float d = __fsub_rn(v[i], mean);
            sq = __fadd_rn(sq, __fmul_rn(d, d));
        }
        const float sig = __fsqrt_rn(__fdiv_rn(pw_reduce64(sq), 575.0f));

        float sa = fabsf(__fdiv_rn(__fsub_rn(v[0], mean), sig));
#pragma unroll
        for (int i = 1; i < 9; i++)
            sa = __fadd_rn(sa, fabsf(__fdiv_rn(__fsub_rn(v[i], mean), sig)));
        const float ma = __fdiv_rn(pw_reduce64(sa), 576.0f);
        const float p  = rintf(log2f(ma));
        if (lane == 0) par[256 + layer * 64 + co] = __fdiv_rn(exp2f(p), 7.0f);

#pragma unroll
        for (int i = 0; i < 9; i++) {
            int ig = base + 8 * i;
            float d = __fsub_rn(v[i], mean);
            int8_t sg = (d > 0.0f) ? (int8_t)1 : ((d < 0.0f) ? (int8_t)-1 : (int8_t)0);
            int ci = ig / 9, tp = ig % 9;
            wb[((((size_t)layer * 4 + (ci >> 4)) * 9 + tp) * 64 + co) * 16 + (ci & 15)] = sg;
        }
    } else {
        if (tid < 128) {
            const int layer = tid >> 6;
            const int c = tid & 63;
            const float* g  = layer ? g2  : g1;
            const float* be = layer ? bb2 : bb1;
            const float* mu = layer ? mm2 : mm1;
            const float* va = layer ? vv2 : vv1;
            const float stdv = __fsqrt_rn(__fadd_rn(va[c], 1e-5f));
            const float w = __fdiv_rn(g[c], stdv);
            const float bb = __fsub_rn(be[c], __fmul_rn(w, mu[c]));
            float aw = fabsf(w), ab = fabsf(bb);
            for (int off = 32; off; off >>= 1) {
                aw = fmaxf(aw, __shfl_xor(aw, off, 64));
                ab = fmaxf(ab, __shfl_xor(ab, off, 64));
            }
            const float Tw = fminf(fmaxf(aw, 1e-10f), 255.0f);
            const float Tb = fminf(fmaxf(ab, 1e-10f), 255.0f);
            {   // quantize(w, 3): n = 7
                float vq = __fdiv_rn(fminf(fmaxf(w, -Tw), Tw), Tw);
                float r  = rintf(__fmul_rn(vq, 7.0f));
                float qf = __fadd_rn(vq, __fsub_rn(__fdiv_rn(r, 7.0f), vq));
                par[layer * 64 + c] = __fmul_rn(qf, Tw);
            }
            {   // quantize(b, 12): n = 4095
                float vq = __fdiv_rn(fminf(fmaxf(bb, -Tb), Tb), Tb);
                float r  = rintf(__fmul_rn(vq, 4095.0f));
                float qf = __fadd_rn(vq, __fsub_rn(__fdiv_rn(r, 4095.0f), vq));
                par[128 + layer * 64 + c] = __fmul_rn(qf, Tb);
            }
        }
    }
}

// ------------------- inline quantize task (bit-identical to old k_quant chain)
// task = (row r, 4-channel group cb4, 4-xcol group xj): produce 4 packed dwords
// d[j] = int8 quant of x[n][4cb4..4cb4+3][r][4xj+j]; zeros for out-of-image rows.
__device__ __forceinline__ void quant_task(const float* __restrict__ x, int n, int r,
                                           int cb4, int xj, float T, double dinv,
                                           unsigned d[4]) {
    if (r >= 0 && r < 56) {
        const float* src = x + ((size_t)(n * 64 + 4 * cb4)) * HW_ + r * 56 + 4 * xj;
        int kq[4][4];
#pragma unroll
        for (int i = 0; i < 4; i++) {
            float4 v = *(const float4*)(src + (size_t)i * HW_);
            const float e[4] = {v.x, v.y, v.z, v.w};
#pragma unroll
            for (int j = 0; j < 4; j++) {
                const float tc = fminf(fmaxf(e[j], -T), T);
                const float u  = (float)((double)tc * dinv);     // == __fdiv_rn(tc, T)
                kq[i][j] = (int)rintf(__fmul_rn(u, 7.0f));
            }
        }
#pragma unroll
        for (int j = 0; j < 4; j++)
            d[j] = (kq[0][j] & 255) | ((kq[1][j] & 255) << 8) |
                   ((kq[2][j] & 255) << 16) | ((unsigned)(kq[3][j] & 255) << 24);
    } else {
#pragma unroll
        for (int j = 0; j < 4; j++) d[j] = 0;
    }
}

// write one quant task's 4 dwords into the chunk-major k0b circular buffer
__device__ __forceinline__ void quant_write(int8_t* k0b, int r, int cb4, int xj,
                                            const unsigned d[4]) {
    int8_t* base = k0b + ((((cb4 >> 2) * 8 + ((r + 2) & 7)) * 58) << 4) + (cb4 & 3) * 4;
#pragma unroll
    for (int j = 0; j < 4; j++)
        *(unsigned*)(base + ((4 * xj + 1 + j) << 4)) = d[j];
}

// faithful f32 epilogue chain (HW-validated Sterbenz-shortened qfn, r11-r13)
#define EPI_CHAIN(S_, scf_, xqv_, qwf_, qbf_, OUT_)                         \
    {   const float Sf_ = (float)(S_);                                      \
        const float convf_ = __fmul_rn(Sf_, scf_);                          \
        const float xb_ = (float)((double)convf_ * (1.0 / 576.0));          \
        const float rr_ = rintf(__fmul_rn(xb_, 1023.0f));                   \
        const float q1_ = (float)((double)rr_ * (1.0 / 1023.0));            \
        const float aq_ = __fmul_rn(q1_, 576.0f);                           \
        float vv_ = __fadd_rn(__fadd_rn(__fmul_rn(aq_, qwf_), qbf_), xqv_); \
        OUT_ = fminf(fmaxf(vv_, -1.0f), 1.0f); }

// ============================ fused quant + conv1 + conv2 block
// Round-13 structure (90 µs, absmax 0.0) with k_quant FUSED IN: staging and
// prefetch now read x (L3-warm from k_pre) and quantize inline with the
// byte-identical chain -- k0 never touches HBM, one dispatch + its launch gap
// and the 50 MB k0 round-trip are gone. MFMA/epilogue core untouched.
__global__ __launch_bounds__(448, 2) void k_fused(const float* __restrict__ x,
                                                  const unsigned* __restrict__ maxbits,
                                                  const int8_t* __restrict__ wb,
                                                  const float* __restrict__ par,
                                                  float* __restrict__ fout) {
    __shared__ __align__(16) int8_t wsm[2 * 4 * 9 * 64 * 16];   // both layers, 73728 B
    __shared__ __align__(16) int8_t k0b[4 * 8 * 58 * 16];       // 29696 B
    __shared__ __align__(16) int8_t x1b[4 * 8 * 58 * 16];       // 29696 B
    __shared__ float lut7[16];                                  // kc/7, kc in [-7,7]
    const int n = blockIdx.x >> 1;
    const int b = (blockIdx.x & 1) * 28;
    const int tid = threadIdx.x;
    const int wv = tid >> 6, lane = tid & 63;
    const int mbase = wv * 32;
    const int ml = lane & 31;
    const int khalf = lane >> 5;
    const int m = mbase + ml;
    const int ym = m / 56, cm = m % 56;

    const float T = fminf(fmaxf(__uint_as_float(*maxbits), 1e-10f), 255.0f);
    const double dinv = 1.0 / (double)T;            // correctly-rounded f64 reciprocal

    // ---- prologue: weights, pads, lut7, then quantize rows b-2..b+3 into k0b
    for (int u = tid; u < 4608; u += 448)
        *(int4*)(wsm + u * 16) = *(const int4*)(wb + (size_t)u * 16);
    if (tid < 64) {     // x1b pad columns x=0,57 zero (never overwritten after)
        const int q = tid & 3, slot = (tid >> 2) & 7, xs = (tid >> 5) & 1;
        *(int4*)(x1b + (((q * 8 + slot) * 58 + xs * 57) << 4)) = (int4){0, 0, 0, 0};
    }
    if (tid >= 64 && tid < 128) {   // k0b pad columns x=0,57 zero, all slots
        const int t2 = tid - 64;
        const int q = t2 & 3, slot = (t2 >> 2) & 7, xs = (t2 >> 5) & 1;
        *(int4*)(k0b + (((q * 8 + slot) * 58 + xs * 57) << 4)) = (int4){0, 0, 0, 0};
    }
    if (tid < 15) lut7[tid] = __fdiv_rn((float)(tid - 7), 7.0f);   // == fdiv(kc,7)
    // staging: 6 rows x 16 cb4 x 14 xj = 1344 tasks = 3/thread
    for (int tt = tid; tt < 1344; tt += 448) {
        const int r6 = tt / 224, rem = tt % 224;
        const int cb4 = rem / 14, xj = rem % 14;
        const int r = b - 2 + r6;
        unsigned d[4];
        quant_task(x, n, r, cb4, xj, T, dinv, d);
        quant_write(k0b, r, cb4, xj, d);
    }
    __syncthreads();

    // ---- per-co parameters hoisted out of the iteration loop
    float qwf1[2], qbf1[2], scf1[2], qwf2[2], qbf2[2], scf2[2];
#pragma unroll
    for (int t = 0; t < 2; t++) {
        const int co = ml + t * 32;
        qwf1[t] = par[co];        qbf1[t] = par[128 + co]; scf1[t] = par[256 + co];
        qwf2[t] = par[64 + co];   qbf2[t] = par[192 + co]; scf2[t] = par[320 + co];
    }

    unsigned pd[2][4];
#pragma unroll 1
    for (int i = 0; i < 8; ++i) {
        // -- A: load + quantize next-4-rows of x into regs (hides under conv1)
        //       896 tasks = exactly 2/thread
        if (i < 7) {
            const int R0 = b + 4 * i + 4;
#pragma unroll
            for (int e2 = 0; e2 < 2; ++e2) {
                const int tt = tid + e2 * 448;
                const int r4 = tt / 224, rem = tt % 224;
                const int cb4 = rem / 14, xj = rem % 14;
                quant_task(x, n, R0 + r4, cb4, xj, T, dinv, pd[e2]);
            }
        }
        // -- B: conv1 chunk i -> x1 rows y1base..y1base+3
        const int y1base = b - 1 + 4 * i;
        {
            v16i acc0, acc1;
#pragma unroll
            for (int z = 0; z < 16; z++) { acc0[z] = 0; acc1[z] = 0; }
            __builtin_amdgcn_s_setprio(1);
#pragma unroll
            for (int s = 0; s < 9; s++) {
                const int ky = s / 3, kx = s % 3;
                const int arow = y1base + ym + ky - 1;          // >= b-2 >= -2
                const int aslot = (arow + 2) & 7;
#pragma unroll
                for (int kb = 0; kb < 2; kb++) {
                    const int q = khalf + 2 * kb;
                    v4i a  = *(const v4i*)(k0b + (((q * 8 + aslot) * 58 + cm + kx) << 4));
                    v4i b0 = *(const v4i*)(wsm + (((q * 9 + s) * 64 + ml) << 4));
                    v4i b1 = *(const v4i*)(wsm + (((q * 9 + s) * 64 + 32 + ml) << 4));
                    acc0 = __builtin_amdgcn_mfma_i32_32x32x32_i8(a, b0, acc0, 0, 0, 0);
                    acc1 = __builtin_amdgcn_mfma_i32_32x32x32_i8(a, b1, acc1, 0, 0, 0);
                }
            }
            __builtin_amdgcn_s_setprio(0);
            // -- C: epilogue1 (T1==1.0 saturation): k2 = rint(out*7) -> x1b
#pragma unroll
            for (int t = 0; t < 2; t++) {
                const int co = ml + t * 32;
                const float qwf = qwf1[t], qbf = qbf1[t], scf = scf1[t];
                const int qc = co >> 4, cl = co & 15;
                const int clw = cl & ~3, cb8 = (cl & 3) * 8;
#pragma unroll
                for (int g = 0; g < 4; g++) {
                    const int mb = mbase + 8 * g + 4 * khalf;   // %4==0, no row straddle
                    const int rl = mb / 56, c0 = mb % 56;
                    const int y1g = y1base + rl;
                    const bool vrow = (y1g >= 0) && (y1g <= 55);   // else zero value
                    const bool wen  = (y1g <= b + 28);             // beyond strip: skip
                    const int ksl = (y1g + 2) & 7;
                    const int xsl = (y1g + 1) & 7;
                    const int resb = (qc * 8 + ksl) * 58 + c0 + 1;
                    const int outb = (qc * 8 + xsl) * 58 + c0 + 1;
#pragma unroll
                    for (int i4 = 0; i4 < 4; i4++) {
                        const int S = t ? acc1[4 * g + i4] : acc0[4 * g + i4];  // |S|<=4032 exact
                        const unsigned wd = *(const unsigned*)(k0b + ((resb + i4) << 4) + clw);
                        const int kc = (int)(int8_t)(wd >> cb8);
                        const float xqv = lut7[kc + 7];            // == __fdiv_rn(kc,7)
                        float val; EPI_CHAIN(S, scf, xqv, qwf, qbf, val);
                        int k2 = (int)rintf(__fmul_rn(val, 7.0f));
                        if (!vrow) k2 = 0;
                        // b16 pair-pack: lane pair (l, l^1) -> one u16 store by even lane
                        const unsigned lowb = (unsigned)(k2 & 255);
                        const unsigned hib  = (unsigned)__shfl_xor((int)(lowb << 8), 1, 64);
                        if (wen && (ml & 1) == 0)
                            *(uint16_t*)(x1b + ((outb + i4) << 4) + (cl & ~1)) =
                                (uint16_t)(lowb | hib);
                    }
                }
            }
        }
        __syncthreads();   // conv1 k0b reads + x1b writes fenced

        // -- E: publish prefetched+quantized rows (slots freed by conv1 chunk i)
        if (i < 7) {
            const int R0 = b + 4 * i + 4;
#pragma unroll
            for (int e2 = 0; e2 < 2; ++e2) {
                const int tt = tid + e2 * 448;
                const int r4 = tt / 224, rem = tt % 224;
                const int cb4 = rem / 14, xj = rem % 14;
                quant_write(k0b, R0 + r4, cb4, xj, pd[e2]);
            }
        }
        // -- F: conv2 chunk i-1 -> out rows y2base..y2base+3 (always in-image)
        if (i >= 1) {
            const int y2base = b + 4 * (i - 1);
            v16i acc0, acc1;
#pragma unroll
            for (int z = 0; z < 16; z++) { acc0[z] = 0; acc1[z] = 0; }
            __builtin_amdgcn_s_setprio(1);
#pragma unroll
            for (int s = 0; s < 9; s++) {
                const int ky = s / 3, kx = s % 3;
                const int arow = y2base + ym + ky - 1;          // >= b-1 >= -1
                const int aslot = (arow + 1) & 7;
#pragma unroll
                for (int kb = 0; kb < 2; kb++) {
                    const int q = khalf + 2 * kb;
                    v4i a  = *(const v4i*)(x1b + (((q * 8 + aslot) * 58 + cm + kx) << 4));
                    v4i b0 = *(const v4i*)(wsm + 36864 + (((q * 9 + s) * 64 + ml) << 4));
                    v4i b1 = *(const v4i*)(wsm + 36864 + (((q * 9 + s) * 64 + 32 + ml) << 4));
                    acc0 = __builtin_amdgcn_mfma_i32_32x32x32_i8(a, b0, acc0, 0, 0, 0);
                    acc1 = __builtin_amdgcn_mfma_i32_32x32x32_i8(a, b1, acc1, 0, 0, 0);
                }
            }
            __builtin_amdgcn_s_setprio(0);
#pragma unroll
            for (int t = 0; t < 2; t++) {
                const int co = ml + t * 32;
                const float qwf = qwf2[t], qbf = qbf2[t], scf = scf2[t];
                const int qc = co >> 4, cl = co & 15;
                const int clw = cl & ~3, cb8 = (cl & 3) * 8;
#pragma unroll
                for (int g = 0; g < 4; g++) {
                    const int mb = mbase + 8 * g + 4 * khalf;
                    const int rl = mb / 56, c0 = mb % 56;
                    const int y2g = y2base + rl;
                    const int xsl = (y2g + 1) & 7;
                    const int resb = (qc * 8 + xsl) * 58 + c0 + 1;
                    float vals[4];
#pragma unroll
                    for (int i4 = 0; i4 < 4; i4++) {
                        const int S = t ? acc1[4 * g + i4] : acc0[4 * g + i4];
                        const unsigned wd = *(const unsigned*)(x1b + ((resb + i4) << 4) + clw);
                        const int kc = (int)(int8_t)(wd >> cb8);
                        const float xqv = lut7[kc + 7];            // == __fdiv_rn(kc,7)
                        EPI_CHAIN(S, scf, xqv, qwf, qbf, vals[i4]);
                    }
                    float4 o = make_float4(vals[0], vals[1], vals[2], vals[3]);
                    *(float4*)(fout + ((size_t)(n * 64 + co)) * HW_ + y2g * 56 + c0) = o;
                }
            }
        }
        if (i < 7) __syncthreads();   // x1b/k0b writes fenced from next iter's readers
    }
}

// ----------------------------------------------------------------- launcher
extern "C" void kernel_launch(void* const* d_in, const int* in_sizes, int n_in,
                              void* d_out, int out_size, void* d_ws, size_t ws_size,
                              hipStream_t stream) {
    const float* x  = (const float*)d_in[0];
    const float* w1 = (const float*)d_in[1];
    const float* w2 = (const float*)d_in[2];
    const float* g1 = (const float*)d_in[3];
    const float* b1 = (const float*)d_in[4];
    const float* m1 = (const float*)d_in[5];
    const float* v1 = (const float*)d_in[6];
    const float* g2 = (const float*)d_in[7];
    const float* b2 = (const float*)d_in[8];
    const float* m2 = (const float*)d_in[9];
    const float* v2 = (const float*)d_in[10];

    char* ws = (char*)d_ws;
    int8_t*  wbp = (int8_t*)(ws + OFF_WB);
    float*   par = (float*)(ws + OFF_PAR);
    unsigned* mx = (unsigned*)(ws + OFF_MAX);

    hipMemsetAsync(mx, 0, 4, stream);
    k_pre<<<1057, 256, 0, stream>>>(x, mx, w1, w2, wbp, par,
                                    g1, b1, m1, v1, g2, b2, m2, v2);
    k_fused<<<B_ * 2, 448, 0, stream>>>(x, mx, wbp, par, (float*)d_out);
}